// Round 5
// baseline (305.065 us; speedup 1.0000x reference)
//
#include <hip/hip_runtime.h>

typedef __attribute__((ext_vector_type(8))) short bf16x8;
typedef __attribute__((ext_vector_type(4))) float f32x4;
typedef unsigned short u16;
typedef unsigned int u32;

#define MFMA16(A, B, C) __builtin_amdgcn_mfma_f32_16x16x32_bf16((A), (B), (C), 0, 0, 0)

#if __has_builtin(__builtin_amdgcn_exp2f)
#define EXP2(x) __builtin_amdgcn_exp2f(x)
#else
#define EXP2(x) exp2f(x)
#endif

__device__ __forceinline__ u16 f2bf(float f) {
  union { float f; unsigned u; } x; x.f = f;
  unsigned r = (x.u + 0x7fffu + ((x.u >> 16) & 1u)) >> 16;
  return (u16)r;
}
__device__ __forceinline__ float bf2f(u16 h) {
  union { float f; unsigned u; } x; x.u = ((unsigned)h) << 16;
  return x.f;
}

// ---------------- prep kernels ----------------

__global__ __launch_bounds__(256) void cast_x_kernel(const float* __restrict__ x,
                                                     u16* __restrict__ xb, int n4) {
  int i = blockIdx.x * 256 + threadIdx.x;
  if (i >= n4) return;
  float4 v = ((const float4*)x)[i];
  ushort4 o;
  o.x = f2bf(v.x); o.y = f2bf(v.y); o.z = f2bf(v.z); o.w = f2bf(v.w);
  ((ushort4*)xb)[i] = o;
}

// W_attn [512][1536] -> wta [1536][512] bf16, tiled 64x64 transpose (coalesced)
__global__ __launch_bounds__(256) void trans_wa_kernel(const float* __restrict__ W,
                                                       u16* __restrict__ wta) {
  __shared__ u16 T[64][72];
  const int n0 = blockIdx.x * 64;   // 24 tiles
  const int k0 = blockIdx.y * 64;   // 8 tiles
  const int tid = threadIdx.x;
  const int r = tid >> 4, c4 = (tid & 15) * 4;
#pragma unroll
  for (int i = 0; i < 4; i++) {
    int row = r + i * 16;
    float4 v = *(const float4*)&W[(size_t)(k0 + row) * 1536 + n0 + c4];
    T[c4 + 0][row] = f2bf(v.x);
    T[c4 + 1][row] = f2bf(v.y);
    T[c4 + 2][row] = f2bf(v.z);
    T[c4 + 3][row] = f2bf(v.w);
  }
  __syncthreads();
  const int row = tid >> 2, c16 = (tid & 3) * 16;
  *(uint4*)&wta[(size_t)(n0 + row) * 512 + k0 + c16]     = *(uint4*)&T[row][c16];
  *(uint4*)&wta[(size_t)(n0 + row) * 512 + k0 + c16 + 8] = *(uint4*)&T[row][c16 + 8];
}

// W_out [512][512] -> whi/wlo [512][512] bf16 transposed, tiled
__global__ __launch_bounds__(256) void trans_wo_kernel(const float* __restrict__ W,
                                                       u16* __restrict__ whi,
                                                       u16* __restrict__ wlo) {
  __shared__ u16 Th[64][72];
  __shared__ u16 Tl[64][72];
  const int n0 = blockIdx.x * 64;
  const int k0 = blockIdx.y * 64;
  const int tid = threadIdx.x;
  const int r = tid >> 4, c4 = (tid & 15) * 4;
#pragma unroll
  for (int i = 0; i < 4; i++) {
    int row = r + i * 16;
    float4 v = *(const float4*)&W[(size_t)(k0 + row) * 512 + n0 + c4];
    float vv[4] = {v.x, v.y, v.z, v.w};
#pragma unroll
    for (int jj = 0; jj < 4; jj++) {
      u16 hi = f2bf(vv[jj]);
      Th[c4 + jj][row] = hi;
      Tl[c4 + jj][row] = f2bf(vv[jj] - bf2f(hi));
    }
  }
  __syncthreads();
  const int row = tid >> 2, c16 = (tid & 3) * 16;
  *(uint4*)&whi[(size_t)(n0 + row) * 512 + k0 + c16]     = *(uint4*)&Th[row][c16];
  *(uint4*)&whi[(size_t)(n0 + row) * 512 + k0 + c16 + 8] = *(uint4*)&Th[row][c16 + 8];
  *(uint4*)&wlo[(size_t)(n0 + row) * 512 + k0 + c16]     = *(uint4*)&Tl[row][c16];
  *(uint4*)&wlo[(size_t)(n0 + row) * 512 + k0 + c16 + 8] = *(uint4*)&Tl[row][c16 + 8];
}

// ---------------- QKV GEMM ----------------
// Q: scaled by 0.125*log2(e), stored [bh][t][64]
// K: stored [bh][t][64]
// V: frag-packed V'[bh][it][ks][d][quad][jj]  (idx = (((bh*16+it)*4+ks)*64+d)*32 + quad*8 + jj)
__global__ __launch_bounds__(256) void gemm_qkv(const u16* __restrict__ xb,
                                                const u16* __restrict__ wta,
                                                const float* __restrict__ b_attn,
                                                u16* __restrict__ q,
                                                u16* __restrict__ kk,
                                                u16* __restrict__ v) {
  __shared__ u16 A_lds[64 * 72];
  __shared__ u16 B_lds[64 * 72];
  const int n0 = blockIdx.x * 64;
  const int m0 = blockIdx.y * 64;
  const int tid  = threadIdx.x;
  const int lane = tid & 63, w = tid >> 6;
  const int wm = w >> 1, wn = w & 1;
  const int quad = lane >> 4, l15 = lane & 15;

  f32x4 acc[2][2] = {};

  for (int k0 = 0; k0 < 512; k0 += 64) {
#pragma unroll
    for (int i = 0; i < 2; i++) {
      int vv = tid + i * 256;            // 0..511
      int row = vv >> 3;
      int cv  = (vv & 7) * 8;
      *(uint4*)&A_lds[row * 72 + cv] = *(const uint4*)(xb  + (size_t)(m0 + row) * 512 + k0 + cv);
      *(uint4*)&B_lds[row * 72 + cv] = *(const uint4*)(wta + (size_t)(n0 + row) * 512 + k0 + cv);
    }
    __syncthreads();
#pragma unroll
    for (int ks = 0; ks < 2; ks++) {
      bf16x8 af[2], bf[2];
#pragma unroll
      for (int ri = 0; ri < 2; ri++)
        af[ri] = *(const bf16x8*)&A_lds[(wm * 32 + ri * 16 + l15) * 72 + ks * 32 + quad * 8];
#pragma unroll
      for (int ci = 0; ci < 2; ci++)
        bf[ci] = *(const bf16x8*)&B_lds[(wn * 32 + ci * 16 + l15) * 72 + ks * 32 + quad * 8];
#pragma unroll
      for (int ri = 0; ri < 2; ri++)
#pragma unroll
        for (int ci = 0; ci < 2; ci++)
          acc[ri][ci] = MFMA16(af[ri], bf[ci], acc[ri][ci]);
    }
    __syncthreads();
  }

  const float QS = 0.18033688011112043f;  // 0.125 * log2(e)
#pragma unroll
  for (int ri = 0; ri < 2; ri++) {
#pragma unroll
    for (int ci = 0; ci < 2; ci++) {
      int n = n0 + wn * 32 + ci * 16 + l15;
      float bias = b_attn[n];
      int chunk = n >> 9;
      int c = n & 511;
      int h = c >> 6, d = c & 63;
      int m_base = m0 + wm * 32 + ri * 16 + quad * 4;
      int b = m_base >> 11, t0 = m_base & 2047;
      int bh = b * 8 + h;
      if (chunk == 0) {
#pragma unroll
        for (int r = 0; r < 4; r++)
          q[(size_t)(bh * 2048 + t0 + r) * 64 + d] = f2bf((acc[ri][ci][r] + bias) * QS);
      } else if (chunk == 1) {
#pragma unroll
        for (int r = 0; r < 4; r++)
          kk[(size_t)(bh * 2048 + t0 + r) * 64 + d] = f2bf(acc[ri][ci][r] + bias);
      } else {
        // V' frag-packed layout
        int it = t0 >> 7, ks2 = (t0 >> 5) & 3, qd = (t0 >> 3) & 3, jj = t0 & 7;
        ushort4 pk;
        pk.x = f2bf(acc[ri][ci][0] + bias);
        pk.y = f2bf(acc[ri][ci][1] + bias);
        pk.z = f2bf(acc[ri][ci][2] + bias);
        pk.w = f2bf(acc[ri][ci][3] + bias);
        size_t idx = ((((size_t)bh * 16 + it) * 4 + ks2) * 64 + d) * 32 + qd * 8 + jj;
        *(ushort4*)&v[idx] = pk;
      }
    }
  }
}

// ---------------- flash attention (barrier-free) ----------------
// grid 1024 blocks (XCD-swizzled (qt,bh)), 256 thr = 4 INDEPENDENT waves.
// Wave = 16 q rows, 128-wide KV tiles. K + V' read direct from global
// (all 4 waves read identical bytes -> L1 dedup). No __syncthreads at all.
// S^T=K·Q^T, no-max exp2 softmax, l via ones-MFMA, P through per-wave LDS.
__global__ __launch_bounds__(256, 3) void flash_attn(const u16* __restrict__ q,
                                                     const u16* __restrict__ k,
                                                     const u16* __restrict__ vt,
                                                     u16* __restrict__ yb) {
  __shared__ u16 P_lds[4 * 16 * 136];  // per-wave [16 q][128 j +pad]

  // XCD-aware swizzle: flat -> (qt, bh) so each XCD owns 4 bh's
  const int flat = blockIdx.y * 32 + blockIdx.x;
  const int xcd = flat & 7, slot = flat >> 3;
  const int bh = xcd * 4 + (slot & 3);
  const int qt = slot >> 2;

  const int tid  = threadIdx.x;
  const int lane = tid & 63, w = tid >> 6;
  const int quad = lane >> 4, l15 = lane & 15;

  const u16* qp = q  + (size_t)bh * 2048 * 64;
  const u16* kp = k  + (size_t)bh * 2048 * 64;
  const u16* vp = vt + (size_t)bh * 131072;

  // Q B-fragments: B[n=l15(q)][kk=quad*8+j]
  bf16x8 qf[2];
#pragma unroll
  for (int ks = 0; ks < 2; ks++)
    qf[ks] = *(const bf16x8*)(qp + (size_t)(qt * 64 + w * 16 + l15) * 64 + ks * 32 + quad * 8);

  f32x4 l_acc = {};
  f32x4 o[4] = {};

  bf16x8 ones;
  {
    short one = (short)0x3F80;
    ones = (bf16x8){one, one, one, one, one, one, one, one};
  }

  u16* Pw = &P_lds[w * 16 * 136];
  const u16* kfrag = kp + (size_t)l15 * 64 + quad * 8;   // + it*8192 + jt*1024 + ks*32

  for (int it = 0; it < 16; it++) {
    const u16* kit = kfrag + it * 8192;
    const u16* vit = vp + it * 8192;

    bf16x8 vf[2][4];
#pragma unroll
    for (int dt = 0; dt < 4; dt++)   // prefetch ks=0 (coalesced, L1-shared)
      vf[0][dt] = *(const bf16x8*)(vit + (dt * 16 + l15) * 32 + quad * 8);

    // S^T streamed over jt: K-frag global load -> MFMA -> exp2 -> pack -> P
#pragma unroll
    for (int jt = 0; jt < 8; jt++) {
      f32x4 s = {0.f, 0.f, 0.f, 0.f};
#pragma unroll
      for (int ks = 0; ks < 2; ks++) {
        bf16x8 kf = *(const bf16x8*)(kit + jt * 1024 + ks * 32);
        s = MFMA16(kf, qf[ks], s);
      }
      u32 pb[4];
#pragma unroll
      for (int r = 0; r < 4; r++) pb[r] = __float_as_uint(EXP2(s[r]));
      uint2 pk;
      pk.x = __builtin_amdgcn_perm(pb[1], pb[0], 0x07060302u);
      pk.y = __builtin_amdgcn_perm(pb[3], pb[2], 0x07060302u);
      *(uint2*)&Pw[l15 * 136 + jt * 16 + quad * 4] = pk;
    }

    // O += P·V ; l += P·1  (vf double-buffered, all global, no barrier)
#pragma unroll
    for (int ks = 0; ks < 4; ks++) {
      if (ks < 3) {
#pragma unroll
        for (int dt = 0; dt < 4; dt++)
          vf[(ks + 1) & 1][dt] = *(const bf16x8*)(vit + (ks + 1) * 2048 + (dt * 16 + l15) * 32 + quad * 8);
      }
      bf16x8 pf = *(const bf16x8*)&Pw[l15 * 136 + ks * 32 + quad * 8];
      l_acc = MFMA16(pf, ones, l_acc);
#pragma unroll
      for (int dt = 0; dt < 4; dt++)
        o[dt] = MFMA16(pf, vf[ks & 1][dt], o[dt]);
    }
  }

  // epilogue: normalize, transpose via per-wave LDS, coalesced uint4 stores
  const int b = bh >> 3, h = bh & 7;
  u32* Tw = (u32*)Pw;   // 16 x 68 u32 tile
#pragma unroll
  for (int r = 0; r < 4; r++) {
    float inv = 1.f / l_acc[r];
#pragma unroll
    for (int dt = 0; dt < 4; dt++) {
      float val = o[dt][r] * inv;
      u16 hi = f2bf(val);
      u16 lo = f2bf(val - bf2f(hi));
      Tw[(quad * 4 + r) * 68 + dt * 16 + l15] = (u32)hi | ((u32)lo << 16);
    }
  }
  int t = qt * 64 + w * 16 + l15;
  size_t rowb = (size_t)(b * 2048 + t) * 512 + h * 64 + quad * 16;
  uint4 g0 = *(uint4*)&Tw[l15 * 68 + quad * 16 + 0];
  uint4 g1 = *(uint4*)&Tw[l15 * 68 + quad * 16 + 4];
  uint4 g2 = *(uint4*)&Tw[l15 * 68 + quad * 16 + 8];
  uint4 g3 = *(uint4*)&Tw[l15 * 68 + quad * 16 + 12];
  uint4 hi4, lo4;
  hi4.x = __builtin_amdgcn_perm(g0.y, g0.x, 0x05040100u);
  hi4.y = __builtin_amdgcn_perm(g0.w, g0.z, 0x05040100u);
  hi4.z = __builtin_amdgcn_perm(g1.y, g1.x, 0x05040100u);
  hi4.w = __builtin_amdgcn_perm(g1.w, g1.z, 0x05040100u);
  lo4.x = __builtin_amdgcn_perm(g0.y, g0.x, 0x07060302u);
  lo4.y = __builtin_amdgcn_perm(g0.w, g0.z, 0x07060302u);
  lo4.z = __builtin_amdgcn_perm(g1.y, g1.x, 0x07060302u);
  lo4.w = __builtin_amdgcn_perm(g1.w, g1.z, 0x07060302u);
  *(uint4*)&yb[rowb] = hi4;
  *(uint4*)&yb[(size_t)4 * 2048 * 512 + rowb] = lo4;
  hi4.x = __builtin_amdgcn_perm(g2.y, g2.x, 0x05040100u);
  hi4.y = __builtin_amdgcn_perm(g2.w, g2.z, 0x05040100u);
  hi4.z = __builtin_amdgcn_perm(g3.y, g3.x, 0x05040100u);
  hi4.w = __builtin_amdgcn_perm(g3.w, g3.z, 0x05040100u);
  lo4.x = __builtin_amdgcn_perm(g2.y, g2.x, 0x07060302u);
  lo4.y = __builtin_amdgcn_perm(g2.w, g2.z, 0x07060302u);
  lo4.z = __builtin_amdgcn_perm(g3.y, g3.x, 0x07060302u);
  lo4.w = __builtin_amdgcn_perm(g3.w, g3.z, 0x07060302u);
  *(uint4*)&yb[rowb + 8] = hi4;
  *(uint4*)&yb[(size_t)4 * 2048 * 512 + rowb + 8] = lo4;
}

// ---------------- output projection (hi/lo split bf16 MFMA) ----------------
__global__ __launch_bounds__(256) void gemm_out(const u16* __restrict__ yhi,
                                                const u16* __restrict__ ylo,
                                                const u16* __restrict__ whi,
                                                const u16* __restrict__ wlo,
                                                const float* __restrict__ b_out,
                                                float* __restrict__ out) {
  __shared__ u16 Ah[64 * 72];
  __shared__ u16 Al[64 * 72];
  __shared__ u16 Bh[64 * 72];
  __shared__ u16 Bl[64 * 72];
  const int n0 = blockIdx.x * 64;
  const int m0 = blockIdx.y * 64;
  const int tid  = threadIdx.x;
  const int lane = tid & 63, w = tid >> 6;
  const int wm = w >> 1, wn = w & 1;
  const int quad = lane >> 4, l15 = lane & 15;

  f32x4 acc[2][2] = {};

  for (int k0 = 0; k0 < 512; k0 += 64) {
#pragma unroll
    for (int i = 0; i < 2; i++) {
      int vv = tid + i * 256;
      int row = vv >> 3;
      int cv  = (vv & 7) * 8;
      *(uint4*)&Ah[row * 72 + cv] = *(const uint4*)(yhi + (size_t)(m0 + row) * 512 + k0 + cv);
      *(uint4*)&Al[row * 72 + cv] = *(const uint4*)(ylo + (size_t)(m0 + row) * 512 + k0 + cv);
      *(uint4*)&Bh[row * 72 + cv] = *(const uint4*)(whi + (size_t)(n0 + row) * 512 + k0 + cv);
      *(uint4*)&Bl[row * 72 + cv] = *(const uint4*)(wlo + (size_t)(n0 + row) * 512 + k0 + cv);
    }
    __syncthreads();
#pragma unroll
    for (int ks = 0; ks < 2; ks++) {
      bf16x8 afh[2], afl[2], bfh[2], bfl[2];
#pragma unroll
      for (int ri = 0; ri < 2; ri++) {
        afh[ri] = *(const bf16x8*)&Ah[(wm * 32 + ri * 16 + l15) * 72 + ks * 32 + quad * 8];
        afl[ri] = *(const bf16x8*)&Al[(wm * 32 + ri * 16 + l15) * 72 + ks * 32 + quad * 8];
      }
#pragma unroll
      for (int ci = 0; ci < 2; ci++) {
        bfh[ci] = *(const bf16x8*)&Bh[(wn * 32 + ci * 16 + l15) * 72 + ks * 32 + quad * 8];
        bfl[ci] = *(const bf16x8*)&Bl[(wn * 32 + ci * 16 + l15) * 72 + ks * 32 + quad * 8];
      }
#pragma unroll
      for (int ri = 0; ri < 2; ri++)
#pragma unroll
        for (int ci = 0; ci < 2; ci++) {
          acc[ri][ci] = MFMA16(afh[ri], bfh[ci], acc[ri][ci]);
          acc[ri][ci] = MFMA16(afh[ri], bfl[ci], acc[ri][ci]);
          acc[ri][ci] = MFMA16(afl[ri], bfh[ci], acc[ri][ci]);
        }
    }
    __syncthreads();
  }

#pragma unroll
  for (int ri = 0; ri < 2; ri++) {
#pragma unroll
    for (int ci = 0; ci < 2; ci++) {
      int n = n0 + wn * 32 + ci * 16 + l15;
      float bias = b_out[n];
#pragma unroll
      for (int r = 0; r < 4; r++) {
        int m = m0 + wm * 32 + ri * 16 + quad * 4 + r;
        out[(size_t)m * 512 + n] = acc[ri][ci][r] + bias;
      }
    }
  }
}

// ---------------- launch ----------------
extern "C" void kernel_launch(void* const* d_in, const int* in_sizes, int n_in,
                              void* d_out, int out_size, void* d_ws, size_t ws_size,
                              hipStream_t stream) {
  const float* x      = (const float*)d_in[0];
  const float* W_attn = (const float*)d_in[1];
  const float* b_attn = (const float*)d_in[2];
  const float* W_out  = (const float*)d_in[3];
  const float* b_out  = (const float*)d_in[4];
  float* out = (float*)d_out;

  char* ws = (char*)d_ws;
  u16* xb   = (u16*)(ws + 0);                 //  8 MB  [8192][512]
  u16* wta  = (u16*)(ws + 8388608);           //  1.5MB [1536][512]
  u16* wtoh = (u16*)(ws + 9961472);           //  0.5MB [512][512]
  u16* wtol = (u16*)(ws + 10485760);          //  0.5MB
  u16* qb   = (u16*)(ws + 11010048);          //  8 MB  [bh][t][64] (pre-scaled)
  u16* kb   = (u16*)(ws + 19398656);          //  8 MB  [bh][t][64]
  u16* vtb  = (u16*)(ws + 27787264);          //  8 MB  V' frag-packed
  u16* yhi  = (u16*)(ws + 36175872);          //  8 MB  [B,T,C] (+8 MB lo plane)

  cast_x_kernel<<<4096, 256, 0, stream>>>(x, xb, 4 * 2048 * 512 / 4);
  trans_wa_kernel<<<dim3(24, 8), 256, 0, stream>>>(W_attn, wta);
  trans_wo_kernel<<<dim3(8, 8), 256, 0, stream>>>(W_out, wtoh, wtol);
  gemm_qkv<<<dim3(24, 128), 256, 0, stream>>>(xb, wta, b_attn, qb, kb, vtb);
  flash_attn<<<dim3(32, 32), 256, 0, stream>>>(qb, kb, vtb, yhi);
  gemm_out<<<dim3(8, 128), 256, 0, stream>>>(yhi, yhi + (size_t)4 * 2048 * 512, wtoh, wtol, b_out, out);
}

// Round 6
// 212.831 us; speedup vs baseline: 1.4334x; 1.4334x over previous
//
#include <hip/hip_runtime.h>

typedef __attribute__((ext_vector_type(8))) short bf16x8;
typedef __attribute__((ext_vector_type(4))) float f32x4;
typedef unsigned short u16;
typedef unsigned int u32;

#define MFMA16(A, B, C) __builtin_amdgcn_mfma_f32_16x16x32_bf16((A), (B), (C), 0, 0, 0)

#if __has_builtin(__builtin_amdgcn_exp2f)
#define EXP2(x) __builtin_amdgcn_exp2f(x)
#else
#define EXP2(x) exp2f(x)
#endif

__device__ __forceinline__ u16 f2bf(float f) {
  union { float f; unsigned u; } x; x.f = f;
  unsigned r = (x.u + 0x7fffu + ((x.u >> 16) & 1u)) >> 16;
  return (u16)r;
}
__device__ __forceinline__ float bf2f(u16 h) {
  union { float f; unsigned u; } x; x.u = ((unsigned)h) << 16;
  return x.f;
}

// ---------------- prep kernels ----------------

__global__ __launch_bounds__(256) void cast_x_kernel(const float* __restrict__ x,
                                                     u16* __restrict__ xb, int n4) {
  int i = blockIdx.x * 256 + threadIdx.x;
  if (i >= n4) return;
  float4 v = ((const float4*)x)[i];
  ushort4 o;
  o.x = f2bf(v.x); o.y = f2bf(v.y); o.z = f2bf(v.z); o.w = f2bf(v.w);
  ((ushort4*)xb)[i] = o;
}

// W_attn [512][1536] -> wta [1536][512] bf16, tiled 64x64 transpose (coalesced)
__global__ __launch_bounds__(256) void trans_wa_kernel(const float* __restrict__ W,
                                                       u16* __restrict__ wta) {
  __shared__ u16 T[64][72];
  const int n0 = blockIdx.x * 64;   // 24 tiles
  const int k0 = blockIdx.y * 64;   // 8 tiles
  const int tid = threadIdx.x;
  const int r = tid >> 4, c4 = (tid & 15) * 4;
#pragma unroll
  for (int i = 0; i < 4; i++) {
    int row = r + i * 16;
    float4 v = *(const float4*)&W[(size_t)(k0 + row) * 1536 + n0 + c4];
    T[c4 + 0][row] = f2bf(v.x);
    T[c4 + 1][row] = f2bf(v.y);
    T[c4 + 2][row] = f2bf(v.z);
    T[c4 + 3][row] = f2bf(v.w);
  }
  __syncthreads();
  const int row = tid >> 2, c16 = (tid & 3) * 16;
  *(uint4*)&wta[(size_t)(n0 + row) * 512 + k0 + c16]     = *(uint4*)&T[row][c16];
  *(uint4*)&wta[(size_t)(n0 + row) * 512 + k0 + c16 + 8] = *(uint4*)&T[row][c16 + 8];
}

// W_out [512][512] -> whi/wlo [512][512] bf16 transposed, tiled
__global__ __launch_bounds__(256) void trans_wo_kernel(const float* __restrict__ W,
                                                       u16* __restrict__ whi,
                                                       u16* __restrict__ wlo) {
  __shared__ u16 Th[64][72];
  __shared__ u16 Tl[64][72];
  const int n0 = blockIdx.x * 64;
  const int k0 = blockIdx.y * 64;
  const int tid = threadIdx.x;
  const int r = tid >> 4, c4 = (tid & 15) * 4;
#pragma unroll
  for (int i = 0; i < 4; i++) {
    int row = r + i * 16;
    float4 v = *(const float4*)&W[(size_t)(k0 + row) * 512 + n0 + c4];
    float vv[4] = {v.x, v.y, v.z, v.w};
#pragma unroll
    for (int jj = 0; jj < 4; jj++) {
      u16 hi = f2bf(vv[jj]);
      Th[c4 + jj][row] = hi;
      Tl[c4 + jj][row] = f2bf(vv[jj] - bf2f(hi));
    }
  }
  __syncthreads();
  const int row = tid >> 2, c16 = (tid & 3) * 16;
  *(uint4*)&whi[(size_t)(n0 + row) * 512 + k0 + c16]     = *(uint4*)&Th[row][c16];
  *(uint4*)&whi[(size_t)(n0 + row) * 512 + k0 + c16 + 8] = *(uint4*)&Th[row][c16 + 8];
  *(uint4*)&wlo[(size_t)(n0 + row) * 512 + k0 + c16]     = *(uint4*)&Tl[row][c16];
  *(uint4*)&wlo[(size_t)(n0 + row) * 512 + k0 + c16 + 8] = *(uint4*)&Tl[row][c16 + 8];
}

// ---------------- QKV GEMM ----------------
// Q: scaled by 0.125*log2(e), stored [bh][t][64]
// K: stored [bh][t][64]
// V: frag-packed V'[bh][it][ks][d][quad][jj]  (idx = (((bh*16+it)*4+ks)*64+d)*32 + quad*8 + jj)
__global__ __launch_bounds__(256) void gemm_qkv(const u16* __restrict__ xb,
                                                const u16* __restrict__ wta,
                                                const float* __restrict__ b_attn,
                                                u16* __restrict__ q,
                                                u16* __restrict__ kk,
                                                u16* __restrict__ v) {
  __shared__ u16 A_lds[64 * 72];
  __shared__ u16 B_lds[64 * 72];
  const int n0 = blockIdx.x * 64;
  const int m0 = blockIdx.y * 64;
  const int tid  = threadIdx.x;
  const int lane = tid & 63, w = tid >> 6;
  const int wm = w >> 1, wn = w & 1;
  const int quad = lane >> 4, l15 = lane & 15;

  f32x4 acc[2][2] = {};

  for (int k0 = 0; k0 < 512; k0 += 64) {
#pragma unroll
    for (int i = 0; i < 2; i++) {
      int vv = tid + i * 256;            // 0..511
      int row = vv >> 3;
      int cv  = (vv & 7) * 8;
      *(uint4*)&A_lds[row * 72 + cv] = *(const uint4*)(xb  + (size_t)(m0 + row) * 512 + k0 + cv);
      *(uint4*)&B_lds[row * 72 + cv] = *(const uint4*)(wta + (size_t)(n0 + row) * 512 + k0 + cv);
    }
    __syncthreads();
#pragma unroll
    for (int ks = 0; ks < 2; ks++) {
      bf16x8 af[2], bf[2];
#pragma unroll
      for (int ri = 0; ri < 2; ri++)
        af[ri] = *(const bf16x8*)&A_lds[(wm * 32 + ri * 16 + l15) * 72 + ks * 32 + quad * 8];
#pragma unroll
      for (int ci = 0; ci < 2; ci++)
        bf[ci] = *(const bf16x8*)&B_lds[(wn * 32 + ci * 16 + l15) * 72 + ks * 32 + quad * 8];
#pragma unroll
      for (int ri = 0; ri < 2; ri++)
#pragma unroll
        for (int ci = 0; ci < 2; ci++)
          acc[ri][ci] = MFMA16(af[ri], bf[ci], acc[ri][ci]);
    }
    __syncthreads();
  }

  const float QS = 0.18033688011112043f;  // 0.125 * log2(e)
#pragma unroll
  for (int ri = 0; ri < 2; ri++) {
#pragma unroll
    for (int ci = 0; ci < 2; ci++) {
      int n = n0 + wn * 32 + ci * 16 + l15;
      float bias = b_attn[n];
      int chunk = n >> 9;
      int c = n & 511;
      int h = c >> 6, d = c & 63;
      int m_base = m0 + wm * 32 + ri * 16 + quad * 4;
      int b = m_base >> 11, t0 = m_base & 2047;
      int bh = b * 8 + h;
      if (chunk == 0) {
#pragma unroll
        for (int r = 0; r < 4; r++)
          q[(size_t)(bh * 2048 + t0 + r) * 64 + d] = f2bf((acc[ri][ci][r] + bias) * QS);
      } else if (chunk == 1) {
#pragma unroll
        for (int r = 0; r < 4; r++)
          kk[(size_t)(bh * 2048 + t0 + r) * 64 + d] = f2bf(acc[ri][ci][r] + bias);
      } else {
        // V' frag-packed layout
        int it = t0 >> 7, ks2 = (t0 >> 5) & 3, qd = (t0 >> 3) & 3, jj = t0 & 7;
        ushort4 pk;
        pk.x = f2bf(acc[ri][ci][0] + bias);
        pk.y = f2bf(acc[ri][ci][1] + bias);
        pk.z = f2bf(acc[ri][ci][2] + bias);
        pk.w = f2bf(acc[ri][ci][3] + bias);
        size_t idx = ((((size_t)bh * 16 + it) * 4 + ks2) * 64 + d) * 32 + qd * 8 + jj;
        *(ushort4*)&v[idx] = pk;
      }
    }
  }
}

// ---------------- flash attention ----------------
// grid 512 blocks (XCD-swizzled), 256 thr (4 waves), wave = 32 q rows,
// 128-wide KV tiles. K double-buffered in LDS, ONE barrier/iter placed so
// vmcnt is already drained (prefetch issued AFTER the barrier -> in flight
// through the whole compute phase, never drained by a barrier).
__global__ __launch_bounds__(256, 2) void flash_attn(const u16* __restrict__ q,
                                                     const u16* __restrict__ k,
                                                     const u16* __restrict__ vt,
                                                     u16* __restrict__ yb) {
  __shared__ u16 K_lds[2][128 * 72];   // double-buffered [j][k +pad]
  __shared__ u16 P_lds[4 * 32 * 136];  // per-wave [32 q][128 j +pad]

  // XCD swizzle: 4 bh per XCD -> K/V working set 2 MB < 4 MB L2
  const int flat = blockIdx.y * 16 + blockIdx.x;
  const int bh = (flat & 7) * 4 + ((flat >> 3) & 3);
  const int qt = flat >> 5;

  const int tid  = threadIdx.x;
  const int lane = tid & 63, w = tid >> 6;
  const int quad = lane >> 4, l15 = lane & 15;

  const u16* qp = q  + (size_t)bh * 131072;
  const u16* kp = k  + (size_t)bh * 131072;
  const u16* vp = vt + (size_t)bh * 131072;

  bf16x8 qf[2][2];
#pragma unroll
  for (int qh = 0; qh < 2; qh++)
#pragma unroll
    for (int ks = 0; ks < 2; ks++)
      qf[qh][ks] = *(const bf16x8*)(qp + (size_t)(qt * 128 + w * 32 + qh * 16 + l15) * 64 + ks * 32 + quad * 8);

  f32x4 l_acc[2] = {};
  f32x4 o[2][4] = {};

  bf16x8 ones;
  {
    short one = (short)0x3F80;
    ones = (bf16x8){one, one, one, one, one, one, one, one};
  }

  u16* Pw = &P_lds[w * 32 * 136];

  uint4 kreg[4];
#pragma unroll
  for (int i = 0; i < 4; i++) {
    int vv = tid + i * 256;
    kreg[i] = *(const uint4*)(kp + (size_t)(vv >> 3) * 64 + (vv & 7) * 8);
  }

  for (int it = 0; it < 16; it++) {
    u16* Kb = K_lds[it & 1];
    // stage tile `it` (kreg consumed here -> vmcnt drained BEFORE the barrier)
#pragma unroll
    for (int i = 0; i < 4; i++) {
      int vv = tid + i * 256;
      *(uint4*)&Kb[(vv >> 3) * 72 + (vv & 7) * 8] = kreg[i];
    }
    __syncthreads();   // cheap: vmcnt already 0, only lgkm + wave sync
    // prefetch tile it+1 -> stays in flight through the whole compute phase
    if (it < 15) {
      const u16* kn = kp + (size_t)(it + 1) * 8192;
#pragma unroll
      for (int i = 0; i < 4; i++) {
        int vv = tid + i * 256;
        kreg[i] = *(const uint4*)(kn + (size_t)(vv >> 3) * 64 + (vv & 7) * 8);
      }
    }

    const u16* vit = vp + it * 8192;
    bf16x8 vf[2][4];
#pragma unroll
    for (int dt = 0; dt < 4; dt++)   // prefetch ks=0 (coalesced 1KB/wave)
      vf[0][dt] = *(const bf16x8*)(vit + (dt * 16 + l15) * 32 + quad * 8);

    // S^T streamed over jt: MFMA -> exp2 -> pack -> P write (8 live s-regs)
#pragma unroll
    for (int jt = 0; jt < 8; jt++) {
      f32x4 s0 = {0.f, 0.f, 0.f, 0.f}, s1 = {0.f, 0.f, 0.f, 0.f};
#pragma unroll
      for (int ks = 0; ks < 2; ks++) {
        bf16x8 kf = *(const bf16x8*)&Kb[(jt * 16 + l15) * 72 + ks * 32 + quad * 8];
        s0 = MFMA16(kf, qf[0][ks], s0);
        s1 = MFMA16(kf, qf[1][ks], s1);
      }
      u32 pb[4];
#pragma unroll
      for (int r = 0; r < 4; r++) pb[r] = __float_as_uint(EXP2(s0[r]));
      uint2 pk0;
      pk0.x = __builtin_amdgcn_perm(pb[1], pb[0], 0x07060302u);
      pk0.y = __builtin_amdgcn_perm(pb[3], pb[2], 0x07060302u);
      *(uint2*)&Pw[l15 * 136 + jt * 16 + quad * 4] = pk0;
#pragma unroll
      for (int r = 0; r < 4; r++) pb[r] = __float_as_uint(EXP2(s1[r]));
      uint2 pk1;
      pk1.x = __builtin_amdgcn_perm(pb[1], pb[0], 0x07060302u);
      pk1.y = __builtin_amdgcn_perm(pb[3], pb[2], 0x07060302u);
      *(uint2*)&Pw[(16 + l15) * 136 + jt * 16 + quad * 4] = pk1;
    }

    // O += P·V ; l += P·1  (vf double-buffered, coalesced)
#pragma unroll
    for (int ks = 0; ks < 4; ks++) {
      if (ks < 3) {
#pragma unroll
        for (int dt = 0; dt < 4; dt++)
          vf[(ks + 1) & 1][dt] = *(const bf16x8*)(vit + (ks + 1) * 2048 + (dt * 16 + l15) * 32 + quad * 8);
      }
      bf16x8 pf0 = *(const bf16x8*)&Pw[l15 * 136 + ks * 32 + quad * 8];
      bf16x8 pf1 = *(const bf16x8*)&Pw[(16 + l15) * 136 + ks * 32 + quad * 8];
      l_acc[0] = MFMA16(pf0, ones, l_acc[0]);
      l_acc[1] = MFMA16(pf1, ones, l_acc[1]);
#pragma unroll
      for (int dt = 0; dt < 4; dt++) {
        o[0][dt] = MFMA16(pf0, vf[ks & 1][dt], o[0][dt]);
        o[1][dt] = MFMA16(pf1, vf[ks & 1][dt], o[1][dt]);
      }
    }
    // no trailing barrier: next iter writes the OTHER K buffer; the following
    // barrier orders buffer reuse two iterations apart.
  }

  // epilogue: normalize, transpose via LDS (reuse Pw), coalesced uint4 stores
  const int b = bh >> 3, h = bh & 7;
  u32* Tw = (u32*)Pw;   // 16 x 68 u32 tile per wave
#pragma unroll
  for (int qh = 0; qh < 2; qh++) {
#pragma unroll
    for (int r = 0; r < 4; r++) {
      float inv = 1.f / l_acc[qh][r];
#pragma unroll
      for (int dt = 0; dt < 4; dt++) {
        float val = o[qh][dt][r] * inv;
        u16 hi = f2bf(val);
        u16 lo = f2bf(val - bf2f(hi));
        Tw[(quad * 4 + r) * 68 + dt * 16 + l15] = (u32)hi | ((u32)lo << 16);
      }
    }
    int t = qt * 128 + w * 32 + qh * 16 + l15;
    size_t rowb = (size_t)(b * 2048 + t) * 512 + h * 64 + quad * 16;
    uint4 g0 = *(uint4*)&Tw[l15 * 68 + quad * 16 + 0];
    uint4 g1 = *(uint4*)&Tw[l15 * 68 + quad * 16 + 4];
    uint4 g2 = *(uint4*)&Tw[l15 * 68 + quad * 16 + 8];
    uint4 g3 = *(uint4*)&Tw[l15 * 68 + quad * 16 + 12];
    uint4 hi4, lo4;
    hi4.x = __builtin_amdgcn_perm(g0.y, g0.x, 0x05040100u);
    hi4.y = __builtin_amdgcn_perm(g0.w, g0.z, 0x05040100u);
    hi4.z = __builtin_amdgcn_perm(g1.y, g1.x, 0x05040100u);
    hi4.w = __builtin_amdgcn_perm(g1.w, g1.z, 0x05040100u);
    lo4.x = __builtin_amdgcn_perm(g0.y, g0.x, 0x07060302u);
    lo4.y = __builtin_amdgcn_perm(g0.w, g0.z, 0x07060302u);
    lo4.z = __builtin_amdgcn_perm(g1.y, g1.x, 0x07060302u);
    lo4.w = __builtin_amdgcn_perm(g1.w, g1.z, 0x07060302u);
    *(uint4*)&yb[rowb] = hi4;
    *(uint4*)&yb[(size_t)4 * 2048 * 512 + rowb] = lo4;
    hi4.x = __builtin_amdgcn_perm(g2.y, g2.x, 0x05040100u);
    hi4.y = __builtin_amdgcn_perm(g2.w, g2.z, 0x05040100u);
    hi4.z = __builtin_amdgcn_perm(g3.y, g3.x, 0x05040100u);
    hi4.w = __builtin_amdgcn_perm(g3.w, g3.z, 0x05040100u);
    lo4.x = __builtin_amdgcn_perm(g2.y, g2.x, 0x07060302u);
    lo4.y = __builtin_amdgcn_perm(g2.w, g2.z, 0x07060302u);
    lo4.z = __builtin_amdgcn_perm(g3.y, g3.x, 0x07060302u);
    lo4.w = __builtin_amdgcn_perm(g3.w, g3.z, 0x07060302u);
    *(uint4*)&yb[rowb + 8] = hi4;
    *(uint4*)&yb[(size_t)4 * 2048 * 512 + rowb + 8] = lo4;
  }
}

// ---------------- output projection (hi/lo split bf16 MFMA) ----------------
__global__ __launch_bounds__(256) void gemm_out(const u16* __restrict__ yhi,
                                                const u16* __restrict__ ylo,
                                                const u16* __restrict__ whi,
                                                const u16* __restrict__ wlo,
                                                const float* __restrict__ b_out,
                                                float* __restrict__ out) {
  __shared__ u16 Ah[64 * 72];
  __shared__ u16 Al[64 * 72];
  __shared__ u16 Bh[64 * 72];
  __shared__ u16 Bl[64 * 72];
  const int n0 = blockIdx.x * 64;
  const int m0 = blockIdx.y * 64;
  const int tid  = threadIdx.x;
  const int lane = tid & 63, w = tid >> 6;
  const int wm = w >> 1, wn = w & 1;
  const int quad = lane >> 4, l15 = lane & 15;

  f32x4 acc[2][2] = {};

  for (int k0 = 0; k0 < 512; k0 += 64) {
#pragma unroll
    for (int i = 0; i < 2; i++) {
      int vv = tid + i * 256;
      int row = vv >> 3;
      int cv  = (vv & 7) * 8;
      *(uint4*)&Ah[row * 72 + cv] = *(const uint4*)(yhi + (size_t)(m0 + row) * 512 + k0 + cv);
      *(uint4*)&Al[row * 72 + cv] = *(const uint4*)(ylo + (size_t)(m0 + row) * 512 + k0 + cv);
      *(uint4*)&Bh[row * 72 + cv] = *(const uint4*)(whi + (size_t)(n0 + row) * 512 + k0 + cv);
      *(uint4*)&Bl[row * 72 + cv] = *(const uint4*)(wlo + (size_t)(n0 + row) * 512 + k0 + cv);
    }
    __syncthreads();
#pragma unroll
    for (int ks = 0; ks < 2; ks++) {
      bf16x8 afh[2], afl[2], bfh[2], bfl[2];
#pragma unroll
      for (int ri = 0; ri < 2; ri++) {
        afh[ri] = *(const bf16x8*)&Ah[(wm * 32 + ri * 16 + l15) * 72 + ks * 32 + quad * 8];
        afl[ri] = *(const bf16x8*)&Al[(wm * 32 + ri * 16 + l15) * 72 + ks * 32 + quad * 8];
      }
#pragma unroll
      for (int ci = 0; ci < 2; ci++) {
        bfh[ci] = *(const bf16x8*)&Bh[(wn * 32 + ci * 16 + l15) * 72 + ks * 32 + quad * 8];
        bfl[ci] = *(const bf16x8*)&Bl[(wn * 32 + ci * 16 + l15) * 72 + ks * 32 + quad * 8];
      }
#pragma unroll
      for (int ri = 0; ri < 2; ri++)
#pragma unroll
        for (int ci = 0; ci < 2; ci++) {
          acc[ri][ci] = MFMA16(afh[ri], bfh[ci], acc[ri][ci]);
          acc[ri][ci] = MFMA16(afh[ri], bfl[ci], acc[ri][ci]);
          acc[ri][ci] = MFMA16(afl[ri], bfh[ci], acc[ri][ci]);
        }
    }
    __syncthreads();
  }

#pragma unroll
  for (int ri = 0; ri < 2; ri++) {
#pragma unroll
    for (int ci = 0; ci < 2; ci++) {
      int n = n0 + wn * 32 + ci * 16 + l15;
      float bias = b_out[n];
#pragma unroll
      for (int r = 0; r < 4; r++) {
        int m = m0 + wm * 32 + ri * 16 + quad * 4 + r;
        out[(size_t)m * 512 + n] = acc[ri][ci][r] + bias;
      }
    }
  }
}

// ---------------- launch ----------------
extern "C" void kernel_launch(void* const* d_in, const int* in_sizes, int n_in,
                              void* d_out, int out_size, void* d_ws, size_t ws_size,
                              hipStream_t stream) {
  const float* x      = (const float*)d_in[0];
  const float* W_attn = (const float*)d_in[1];
  const float* b_attn = (const float*)d_in[2];
  const float* W_out  = (const float*)d_in[3];
  const float* b_out  = (const float*)d_in[4];
  float* out = (float*)d_out;

  char* ws = (char*)d_ws;
  u16* xb   = (u16*)(ws + 0);                 //  8 MB  [8192][512]
  u16* wta  = (u16*)(ws + 8388608);           //  1.5MB [1536][512]
  u16* wtoh = (u16*)(ws + 9961472);           //  0.5MB [512][512]
  u16* wtol = (u16*)(ws + 10485760);          //  0.5MB
  u16* qb   = (u16*)(ws + 11010048);          //  8 MB  [bh][t][64] (pre-scaled)
  u16* kb   = (u16*)(ws + 19398656);          //  8 MB  [bh][t][64]
  u16* vtb  = (u16*)(ws + 27787264);          //  8 MB  V' frag-packed
  u16* yhi  = (u16*)(ws + 36175872);          //  8 MB  [B,T,C] (+8 MB lo plane)

  cast_x_kernel<<<4096, 256, 0, stream>>>(x, xb, 4 * 2048 * 512 / 4);
  trans_wa_kernel<<<dim3(24, 8), 256, 0, stream>>>(W_attn, wta);
  trans_wo_kernel<<<dim3(8, 8), 256, 0, stream>>>(W_out, wtoh, wtol);
  gemm_qkv<<<dim3(24, 128), 256, 0, stream>>>(xb, wta, b_attn, qb, kb, vtb);
  flash_attn<<<dim3(16, 32), 256, 0, stream>>>(qb, kb, vtb, yhi);
  gemm_out<<<dim3(8, 128), 256, 0, stream>>>(yhi, yhi + (size_t)4 * 2048 * 512, wtoh, wtol, b_out, out);
}